// Round 9
// baseline (111.915 us; speedup 1.0000x reference)
//
#include <hip/hip_runtime.h>
#include <math.h>

// Morphological dilation, k=4x4, TF SAME padding (pad top/left=1, bottom/right=2).
// x: (8, 512, 512, 32) fp32 NHWC;  w: (4, 4, 32) fp32;  out: same as x.
// out[b,y,x,c] = max_{i,j} x[b, y+i-1, x+j-1, c] + w[i,j,c]  (OOB -> -inf)
//
// Structure lesson (R4..R7): fully-unrolled y-strip sustains ~6 TB/s logical;
// ring/runtime-loop variants lose MLP (compiler sinks loads; VGPR=32/48).
// T=16 is the halo/pressure sweet spot (R4 = 97.4 us). R9 (=R8 fixed):
// thread owns a float2 channel-pair -> dwordx2 loads (512 B/wave-instr),
// halving load-instr count + addressing + select overhead per byte.
// NT store needs a native vector type (ext_vector_type), not HIP float2.

constexpr int H = 512;
constexpr int W = 512;
constexpr int C = 32;
constexpr int T = 16;  // output rows per thread (y-strip)

typedef float f2_native __attribute__((ext_vector_type(2)));

__device__ __forceinline__ float2 fmax2(float2 a, float2 b) {
    return make_float2(fmaxf(a.x, b.x), fmaxf(a.y, b.y));
}
__device__ __forceinline__ float2 fadd2(float2 a, float2 b) {
    return make_float2(a.x + b.x, a.y + b.y);
}

template<bool EDGE>
__device__ __forceinline__ void dil_body(const float* __restrict__ xb,
                                         const float2 wv[16],
                                         float2 acc[T],
                                         const int y0, const int xp) {
    const float2 NEG = make_float2(-INFINITY, -INFINITY);
#pragma unroll
    for (int r = 0; r < T + 3; ++r) {
        int yy = y0 - 1 + r;
        bool yok = true;
        if (EDGE) {
            yok = ((unsigned)yy < (unsigned)H);
            yy = min(max(yy, 0), H - 1);          // safe clamped address
        }
        const float* rowp = xb + (size_t)yy * (W * C);

        float2 px[4];
#pragma unroll
        for (int j = 0; j < 4; ++j) {
            int xx = xp + j - 1;
            if (EDGE) {
                bool ok = yok & ((unsigned)xx < (unsigned)W);
                xx = min(max(xx, 0), W - 1);
                float2 v = *reinterpret_cast<const float2*>(rowp + (size_t)xx * C);
                px[j] = ok ? v : NEG;
            } else {
                px[j] = *reinterpret_cast<const float2*>(rowp + (size_t)xx * C);
            }
        }

#pragma unroll
        for (int i = 0; i < 4; ++i) {
            const int t = r - i;            // unroll-constant: static acc index
            if (t < 0 || t >= T) continue;  // folded at compile time
            float2 v = fmax2(fmax2(fadd2(px[0], wv[i * 4 + 0]),
                                   fadd2(px[1], wv[i * 4 + 1])),
                             fmax2(fadd2(px[2], wv[i * 4 + 2]),
                                   fadd2(px[3], wv[i * 4 + 3])));
            acc[t] = fmax2(acc[t], v);
        }
    }
}

__global__ void dil2d_kernel(const float* __restrict__ xin,
                             const float* __restrict__ wt,
                             float* __restrict__ out) {
    // thread -> (channel-pair, x): lanes walk c then x
    // -> 64 lanes x 8 B = 512 B contiguous per wave load instruction.
    const int c2 = (threadIdx.x & 15) * 2;       // channel base 0,2,...,30
    const int xl = threadIdx.x >> 4;             // 0..15
    const int xp = blockIdx.x * 16 + xl;         // 0..511
    const int y0 = blockIdx.y * T;               // strip start row
    const int b  = blockIdx.z;

    // 4x4 weight taps for our channel pair in registers (32 VGPRs)
    float2 wv[16];
#pragma unroll
    for (int k = 0; k < 16; ++k)
        wv[k] = *reinterpret_cast<const float2*>(wt + k * C + c2);

    float2 acc[T];
#pragma unroll
    for (int t = 0; t < T; ++t) acc[t] = make_float2(-INFINITY, -INFINITY);

    const float* xb = xin + (size_t)b * H * W * C + c2;

    // wave-uniform edge classification: interior blocks take the
    // zero-bounds-logic straight-line path.
    const bool yedge = (blockIdx.y == 0) || (blockIdx.y == gridDim.y - 1);
    const bool xedge = (blockIdx.x == 0) || (blockIdx.x == gridDim.x - 1);

    if (yedge | xedge) dil_body<true >(xb, wv, acc, y0, xp);
    else               dil_body<false>(xb, wv, acc, y0, xp);

    float* ob = out + (((size_t)b * H + y0) * W + xp) * C + c2;
#pragma unroll
    for (int t = 0; t < T; ++t) {
        f2_native v;
        v.x = acc[t].x;
        v.y = acc[t].y;
        __builtin_nontemporal_store(
            v, reinterpret_cast<f2_native*>(ob + (size_t)t * W * C));
    }
}

extern "C" void kernel_launch(void* const* d_in, const int* in_sizes, int n_in,
                              void* d_out, int out_size, void* d_ws, size_t ws_size,
                              hipStream_t stream) {
    const float* x = (const float*)d_in[0];
    const float* w = (const float*)d_in[1];
    float* o = (float*)d_out;

    dim3 block(256);
    dim3 grid(W / 16,   // 32: x tiles (16 x-positions per block)
              H / T,    // 32: y strips
              8);       // batch
    dil2d_kernel<<<grid, block, 0, stream>>>(x, w, o);
}